// Round 6
// baseline (77.355 us; speedup 1.0000x reference)
//
#include <hip/hip_runtime.h>
#include <math.h>

#define BATCH 32
#define CH    128
#define HW    4096   // 64*64

typedef short short8 __attribute__((ext_vector_type(8)));   // 8 bf16 (4 VGPRs)
typedef float f32x4  __attribute__((ext_vector_type(4)));   // MFMA accumulator

#define SWZ(n) ((((n) >> 2) & 7) << 3)   // XOR swizzle of k-index by row

__device__ __forceinline__ unsigned short f2bf(float f) {   // RNE float->bf16
    unsigned int u = __float_as_uint(f);
    u = (u + 0x7FFF + ((u >> 16) & 1)) >> 16;
    return (unsigned short)u;
}
__device__ __forceinline__ float bf2f(unsigned short s) {
    return __uint_as_float(((unsigned int)s) << 16);
}
__device__ __forceinline__ float comp(const float4& v, int r) {  // static r after unroll
    return (r == 0) ? v.x : (r == 1) ? v.y : (r == 2) ? v.z : v.w;
}

// ---------------------------------------------------------------------------
// Kernel 1: pooled[b*C+c] = mean over HW of condition[b,c,:,:]
// ---------------------------------------------------------------------------
__global__ __launch_bounds__(256) void pool_kernel(const float* __restrict__ cond,
                                                   float* __restrict__ pooled) {
    int bc = blockIdx.x;
    const float4* base = (const float4*)(cond + (size_t)bc * HW);
    int tid = threadIdx.x;
    float s = 0.f;
#pragma unroll
    for (int k = 0; k < 4; ++k) {
        float4 v = base[tid + k * 256];
        s += v.x + v.y + v.z + v.w;
    }
    for (int off = 32; off; off >>= 1) s += __shfl_down(s, off, 64);
    __shared__ float red[4];
    if ((tid & 63) == 0) red[tid >> 6] = s;
    __syncthreads();
    if (tid == 0) pooled[bc] = (red[0] + red[1] + red[2] + red[3]) * (1.0f / HW);
}

// ---------------------------------------------------------------------------
// Kernel 2: wmat[b][o][i] = dot(pooled[b], w_lin[o*C+i]) + b_lin + (o==i)
// fp32 copy for logdet diagonal + bf16 copy for both MFMA consumers.
// ---------------------------------------------------------------------------
__global__ __launch_bounds__(256) void wmat_kernel(const float* __restrict__ pooled,
                                                   const float* __restrict__ w_lin,
                                                   const float* __restrict__ b_lin,
                                                   float* __restrict__ wmat,
                                                   unsigned short* __restrict__ wmatb) {
    __shared__ float4 pl[BATCH * CH / 4];   // pooled staged: pl[b*32 + k4]
    int tid = threadIdx.x;
    const float4* p4 = (const float4*)pooled;
    for (int idx = tid; idx < BATCH * CH / 4; idx += 256) pl[idx] = p4[idx];
    __syncthreads();

    int n = blockIdx.x * 256 + tid;
    const float4* row = (const float4*)(w_lin + (size_t)n * CH);
    float bl = b_lin[n];
    float acc[BATCH];
#pragma unroll
    for (int b = 0; b < BATCH; ++b) acc[b] = bl;

    for (int k4 = 0; k4 < CH / 4; ++k4) {
        float4 wv = row[k4];
#pragma unroll
        for (int b = 0; b < BATCH; ++b) {
            float4 pv = pl[b * 32 + k4];
            acc[b] += pv.x * wv.x + pv.y * wv.y + pv.z * wv.z + pv.w * wv.w;
        }
    }
    int o = n >> 7, i = n & 127;
    float diag = (o == i) ? 1.0f : 0.0f;
#pragma unroll
    for (int b = 0; b < BATCH; ++b) {
        float v = acc[b] + diag;
        wmat [(size_t)b * (CH * CH) + n] = v;
        wmatb[(size_t)b * (CH * CH) + n] = f2bf(v);
    }
}

// ---------------------------------------------------------------------------
// Kernel 3 (fused):
//   blocks 0..31: per-sample log|det W| via MFMA series (round-4, validated).
//   blocks 32..543: MFMA conv, 2 tiles (256 pix) per block, T14 pipeline:
//     prologue-load tile0 (regs) -> [convert->LDS(buf t); issue loads tile
//     t+1; barrier; MFMA+store tile t]. Reg-staged global loads stay in
//     flight across the barrier, keeping HBM fed during compute.
// ---------------------------------------------------------------------------
__global__ __launch_bounds__(256) void fused_kernel(const float* __restrict__ inp,
                                                    const float* __restrict__ wmat,
                                                    const unsigned short* __restrict__ wmatb,
                                                    float* __restrict__ out,
                                                    float* __restrict__ partial) {
    __shared__ __align__(16) short Xsh[2 * 128 * 136];   // 2 x 34816 B
    int tid  = threadIdx.x;
    int lane = tid & 63;
    int ln   = lane & 15;                // row/col within 16
    int lg   = lane >> 4;                // k-group 0..3
    int och0 = (tid >> 6) * 32;          // wave's m-base

    if (blockIdx.x < BATCH) {
        // ---------------- logdet (MFMA series) ----------------
        short* X = Xsh;                  // buffer 0 only
        int b = blockIdx.x;
        const float*          Wb = wmat  + (size_t)b * CH * CH;
        const unsigned short* wb = wmatb + (size_t)b * CH * CH;

        // ---- stage ÊT[n][k^swz] = Ê[k][n], diag zeroed (transpose of W rows)
        {
            int q  = tid & 31;           // col-quad: n = 4q..4q+3
            int ks = tid >> 5;           // 0..7
            const float* sb = Wb + 4 * q;
#pragma unroll
            for (int m = 0; m < 4; ++m) {
                int k0 = m * 32 + ks * 4;
                float4 r0 = *(const float4*)(sb + (size_t)(k0 + 0) * CH);
                float4 r1 = *(const float4*)(sb + (size_t)(k0 + 1) * CH);
                float4 r2 = *(const float4*)(sb + (size_t)(k0 + 2) * CH);
                float4 r3 = *(const float4*)(sb + (size_t)(k0 + 3) * CH);
#pragma unroll
                for (int r = 0; r < 4; ++r) {
                    int n = 4 * q + r;
                    float a0 = comp(r0, r), a1 = comp(r1, r);
                    float a2 = comp(r2, r), a3 = comp(r3, r);
                    if (k0 + 0 == n) a0 = 0.f;
                    if (k0 + 1 == n) a1 = 0.f;
                    if (k0 + 2 == n) a2 = 0.f;
                    if (k0 + 3 == n) a3 = 0.f;
                    ushort4 v;
                    v.x = f2bf(a0); v.y = f2bf(a1); v.z = f2bf(a2); v.w = f2bf(a3);
                    *(ushort4*)&X[n * 136 + (k0 ^ SWZ(n))] = v;
                }
            }
        }

        // ---- A fragments: Ê rows from wmatb, diag slot zeroed
        short8 afr[2][4];
#pragma unroll
        for (int mt = 0; mt < 2; ++mt) {
            int row = och0 + mt * 16 + ln;
#pragma unroll
            for (int g = 0; g < 4; ++g) {
                short8 v = *(const short8*)&wb[(size_t)row * CH + g * 32 + lg * 8];
#pragma unroll
                for (int j = 0; j < 8; ++j)
                    if (g * 32 + lg * 8 + j == row) v[j] = 0;
                afr[mt][g] = v;
            }
        }
        __syncthreads();

        // ---- D = Ê² via MFMA
        f32x4 acc[2][8];
#pragma unroll
        for (int mt = 0; mt < 2; ++mt)
#pragma unroll
            for (int nt = 0; nt < 8; ++nt) acc[mt][nt] = (f32x4){0.f, 0.f, 0.f, 0.f};
#pragma unroll
        for (int g = 0; g < 4; ++g) {
#pragma unroll
            for (int nt = 0; nt < 8; ++nt) {
                int n = nt * 16 + ln;
                short8 bfr = *(const short8*)&X[n * 136 + ((g * 32 + lg * 8) ^ SWZ(n))];
                acc[0][nt] = __builtin_amdgcn_mfma_f32_16x16x32_bf16(afr[0][g], bfr, acc[0][nt], 0, 0, 0);
                acc[1][nt] = __builtin_amdgcn_mfma_f32_16x16x32_bf16(afr[1][g], bfr, acc[1][nt], 0, 0, 0);
            }
        }

        // ---- traces: t3 (ÊT still in LDS) + diagonal terms
        float ld = 0.f;
#pragma unroll
        for (int mt = 0; mt < 2; ++mt) {
#pragma unroll
            for (int nt = 0; nt < 8; ++nt) {
#pragma unroll
                for (int reg = 0; reg < 4; ++reg) {
                    int row = och0 + mt * 16 + lg * 4 + reg;
                    int col = nt * 16 + ln;
                    float v = acc[mt][nt][reg];
                    float eT = bf2f((unsigned short)X[row * 136 + (col ^ SWZ(row))]); // Ê[col][row]
                    ld += v * eT * (1.f / 3.f);
                    if (row == col) {
                        float d = Wb[(size_t)row * CH + row] - 1.0f;
                        ld += logf(fabsf(1.f + d)) + v * d - 0.5f * v;
                    }
                }
            }
        }
        __syncthreads();   // all ÊT reads done -> reuse LDS for D

        // ---- write D (bf16) for the transpose needed by tr(Ê⁴)
#pragma unroll
        for (int mt = 0; mt < 2; ++mt)
#pragma unroll
            for (int nt = 0; nt < 8; ++nt)
#pragma unroll
                for (int reg = 0; reg < 4; ++reg) {
                    int row = och0 + mt * 16 + lg * 4 + reg;
                    int col = nt * 16 + ln;
                    X[row * 136 + (col ^ SWZ(row))] = (short)f2bf(acc[mt][nt][reg]);
                }
        __syncthreads();

        // ---- t4 = sum D[r][c]*D[c][r]
#pragma unroll
        for (int mt = 0; mt < 2; ++mt)
#pragma unroll
            for (int nt = 0; nt < 8; ++nt)
#pragma unroll
                for (int reg = 0; reg < 4; ++reg) {
                    int row = och0 + mt * 16 + lg * 4 + reg;
                    int col = nt * 16 + ln;
                    float dT = bf2f((unsigned short)X[col * 136 + (row ^ SWZ(col))]); // D[col][row]
                    ld -= acc[mt][nt][reg] * dT * 0.25f;
                }

        for (int off = 32; off; off >>= 1) ld += __shfl_down(ld, off, 64);
        __syncthreads();   // all D reads done -> reuse LDS head for reduction
        float* red = (float*)Xsh;
        if (lane == 0) red[tid >> 6] = ld;
        __syncthreads();
        if (tid == 0) partial[b] = red[0] + red[1] + red[2] + red[3];
    } else {
        // ---------------- MFMA conv, 2-tile T14 pipeline ----------------
        int cb   = blockIdx.x - BATCH;
        int b    = cb >> 4;                  // 0..31
        int pair = cb & 15;                  // 0..15
        int pix0 = pair * 256;

        // A fragments (W bf16 rows), loaded once, reused for both tiles
        const unsigned short* wb = wmatb + (size_t)b * CH * CH;
        short8 afr[2][4];
#pragma unroll
        for (int mt = 0; mt < 2; ++mt)
#pragma unroll
            for (int g = 0; g < 4; ++g)
                afr[mt][g] = *(const short8*)&wb[(size_t)(och0 + mt * 16 + ln) * CH + g * 32 + lg * 8];

        int q  = tid & 31;                   // pixel-quad: pix = 4q..4q+3
        int ks = tid >> 5;                   // 0..7
        const float* sb = inp + (size_t)b * CH * HW + pix0 + 4 * q;

        // ---- prologue: load tile 0 into registers
        float4 stg[16];
#pragma unroll
        for (int m = 0; m < 4; ++m) {
            int k0 = m * 32 + ks * 4;
#pragma unroll
            for (int r = 0; r < 4; ++r)
                stg[m * 4 + r] = *(const float4*)(sb + (size_t)(k0 + r) * HW);
        }

#pragma unroll
        for (int t = 0; t < 2; ++t) {
            short* Xb = Xsh + t * (128 * 136);

            // ---- convert stg -> bf16 LDS [pix][k^swz] (4x4 transpose)
#pragma unroll
            for (int m = 0; m < 4; ++m) {
                int k0 = m * 32 + ks * 4;
#pragma unroll
                for (int r = 0; r < 4; ++r) {
                    int pix = 4 * q + r;
                    ushort4 v;
                    v.x = f2bf(comp(stg[m * 4 + 0], r));
                    v.y = f2bf(comp(stg[m * 4 + 1], r));
                    v.z = f2bf(comp(stg[m * 4 + 2], r));
                    v.w = f2bf(comp(stg[m * 4 + 3], r));
                    *(ushort4*)&Xb[pix * 136 + (k0 ^ SWZ(pix))] = v;
                }
            }

            // ---- issue tile-1 loads; they stay in flight across the barrier
            if (t == 0) {
#pragma unroll
                for (int m = 0; m < 4; ++m) {
                    int k0 = m * 32 + ks * 4;
#pragma unroll
                    for (int r = 0; r < 4; ++r)
                        stg[m * 4 + r] = *(const float4*)(sb + 128 + (size_t)(k0 + r) * HW);
                }
            }
            __syncthreads();

            // ---- MFMA: 2 m-tiles x 8 n-tiles x 4 k-steps
            f32x4 acc[2][8];
#pragma unroll
            for (int mt = 0; mt < 2; ++mt)
#pragma unroll
                for (int nt = 0; nt < 8; ++nt) acc[mt][nt] = (f32x4){0.f, 0.f, 0.f, 0.f};
#pragma unroll
            for (int g = 0; g < 4; ++g) {
#pragma unroll
                for (int nt = 0; nt < 8; ++nt) {
                    int pix = nt * 16 + ln;
                    short8 bfr = *(const short8*)&Xb[pix * 136 + ((g * 32 + lg * 8) ^ SWZ(pix))];
                    acc[0][nt] = __builtin_amdgcn_mfma_f32_16x16x32_bf16(afr[0][g], bfr, acc[0][nt], 0, 0, 0);
                    acc[1][nt] = __builtin_amdgcn_mfma_f32_16x16x32_bf16(afr[1][g], bfr, acc[1][nt], 0, 0, 0);
                }
            }

            // ---- store: D row = lg*4 + reg (och), col = ln (pix)
            float* ob = out + (size_t)b * CH * HW + pix0 + t * 128;
#pragma unroll
            for (int mt = 0; mt < 2; ++mt) {
#pragma unroll
                for (int nt = 0; nt < 8; ++nt) {
                    int och = och0 + mt * 16 + lg * 4;
                    int px  = nt * 16 + ln;
#pragma unroll
                    for (int r = 0; r < 4; ++r)
                        ob[(size_t)(och + r) * HW + px] = acc[mt][nt][r];
                }
            }
            // no end-of-iter barrier needed: iter1 writes buffer 1, never
            // touched before; buffer 0 is never rewritten.
        }
    }
}

// ---------------------------------------------------------------------------
// Kernel 4: log_det = HW * mean_b(partial[b]) = sum * 128
// ---------------------------------------------------------------------------
__global__ void finalize_kernel(const float* __restrict__ partial,
                                float* __restrict__ out_scalar) {
    int tid = threadIdx.x;
    float v = (tid < BATCH) ? partial[tid] : 0.f;
    for (int off = 32; off; off >>= 1) v += __shfl_down(v, off, 64);
    if (tid == 0) out_scalar[0] = v * 128.0f;
}

// ---------------------------------------------------------------------------
extern "C" void kernel_launch(void* const* d_in, const int* in_sizes, int n_in,
                              void* d_out, int out_size, void* d_ws, size_t ws_size,
                              hipStream_t stream) {
    const float* inp   = (const float*)d_in[0];
    const float* cond  = (const float*)d_in[1];
    const float* w_lin = (const float*)d_in[2];
    const float* b_lin = (const float*)d_in[3];
    float* out = (float*)d_out;

    float* pooled          = (float*)d_ws;                    // 4096 floats
    float* wmat            = pooled + BATCH * CH;             // 524288 floats
    float* partial         = wmat + BATCH * CH * CH;          // 32 floats
    unsigned short* wmatb  = (unsigned short*)(partial + 64); // 524288 bf16

    pool_kernel<<<BATCH * CH, 256, 0, stream>>>(cond, pooled);
    wmat_kernel<<<CH * CH / 256, 256, 0, stream>>>(pooled, w_lin, b_lin, wmat, wmatb);
    fused_kernel<<<BATCH + 512, 256, 0, stream>>>(inp, wmat, wmatb, out, partial);
    finalize_kernel<<<1, 64, 0, stream>>>(partial, out + (size_t)BATCH * CH * HW);
}